// Round 11
// baseline (345.234 us; speedup 1.0000x reference)
//
#include <hip/hip_runtime.h>
#include <hip/hip_bf16.h>

#define NB   32
#define SEQ  512
#define HID  768
#define FFN  3072
#define NEXP 8

typedef float f32x4 __attribute__((ext_vector_type(4)));
typedef short s16x8 __attribute__((ext_vector_type(8)));

__device__ __forceinline__ unsigned short f2bf(float f) {
    return __builtin_bit_cast(unsigned short, (__bf16)f);
}

__device__ __forceinline__ float fast_exp2(float x) {
    float r; asm("v_exp_f32 %0, %1" : "=v"(r) : "v"(x)); return r;
}
__device__ __forceinline__ float fast_rcp(float x) {
    float r; asm("v_rcp_f32 %0, %1" : "=v"(r) : "v"(x)); return r;
}

// tanh-gelu, overflow-free (exp2 arg <= 0). |error| vs exact-erf gelu ~2e-4.
__device__ __forceinline__ float gelu_fast(float v) {
    float u  = v * (0.7978845608f + 0.0356774081f * v * v);
    float t  = fast_exp2(-2.8853900817779268f * fabsf(u));
    float T  = (1.0f - t) * fast_rcp(1.0f + t);
    return 0.5f * v + 0.5f * fabsf(v) * T;
}

#define GLOAD16(gp, lp) __builtin_amdgcn_global_load_lds( \
    (const __attribute__((address_space(1))) unsigned int*)(gp), \
    (__attribute__((address_space(3))) unsigned int*)(lp), 16, 0, 0)

#define VMCNT(N) asm volatile("s_waitcnt vmcnt(%0)" :: "i"(N) : "memory")

// ---------------------------------------------------------------------------
// stable counting-sort permutation of sentences by expert label (1 wave)
// ---------------------------------------------------------------------------
__global__ void sort_labels_kernel(const int* __restrict__ labels, int* __restrict__ perm)
{
    int i = threadIdx.x;
    if (i < NB) {
        int li = labels[i];
        int rank = 0;
        for (int j = 0; j < NB; j++) {
            int lj = labels[j];
            if (lj < li || (lj == li && j < i)) rank++;
        }
        perm[rank] = i;
    }
}

// ---------------------------------------------------------------------------
// convert X fp32 -> bf16 (full-chip)
// ---------------------------------------------------------------------------
__global__ __launch_bounds__(256) void cvt_x_kernel(
    const float* __restrict__ X, unsigned short* __restrict__ Xb, int n8)
{
    int idx = blockIdx.x * blockDim.x + threadIdx.x;
    int stride = gridDim.x * blockDim.x;
    for (int i = idx; i < n8; i += stride) {
        f32x4 a = *(const f32x4*)(X + (size_t)i * 8);
        f32x4 b = *(const f32x4*)(X + (size_t)i * 8 + 4);
        unsigned short o[8];
#pragma unroll
        for (int v = 0; v < 4; v++) o[v] = f2bf(a[v]);
#pragma unroll
        for (int v = 0; v < 4; v++) o[4 + v] = f2bf(b[v]);
        *(s16x8*)(Xb + (size_t)i * 8) = *(s16x8*)o;
    }
}

// ---------------------------------------------------------------------------
// convert + transpose: in [R][C] fp32 -> out [C][R] bf16 per slab
// ---------------------------------------------------------------------------
__global__ __launch_bounds__(256) void cvt_transpose_kernel(
    const float* __restrict__ W, unsigned short* __restrict__ WT, int R, int C)
{
    __shared__ unsigned short tile[64][65];
    const int cb = blockIdx.x * 64, rb = blockIdx.y * 64;
    const float* src = W + (size_t)blockIdx.z * R * C;
    unsigned short* dst = WT + (size_t)blockIdx.z * R * C;
    const int x = threadIdx.x & 63, y0 = threadIdx.x >> 6;
#pragma unroll
    for (int i = 0; i < 16; i++) {
        int r = y0 + i * 4;
        tile[r][x] = f2bf(src[(size_t)(rb + r) * C + cb + x]);
    }
    __syncthreads();
#pragma unroll
    for (int i = 0; i < 16; i++) {
        int c = y0 + i * 4;
        dst[(size_t)(cb + c) * R + rb + x] = tile[x][c];
    }
}

// ---------------------------------------------------------------------------
// 256x256 8-phase GEMM window machinery (BK=64, 8 waves, 2 x 64KB LDS bufs)
// ---------------------------------------------------------------------------
template<int LDB, bool ISA>
__device__ __forceinline__ void stage_region(const char* g, char* lds, int half, int tid)
{
#pragma unroll
    for (int p = 0; p < 2; p++) {
        int L  = p * 8192 + tid * 16;
        int rr = L >> 7;
        int cb = L & 127;
        int row = ISA ? ((rr & 63) + ((rr >> 6) << 7) + half * 64)
                      : ((rr & 31) + ((rr >> 5) << 6) + half * 32);
        int cbs = cb ^ ((row & 7) << 4);
        GLOAD16(g + (size_t)row * LDB + cbs, lds + (size_t)row * 128 + cb);
    }
}

__device__ __forceinline__ void read_af(const char* Ab, int arow_b, int k0, int ih, s16x8 (&a)[2][4])
{
    const int k1 = k0 ^ 64;
#pragma unroll
    for (int i = 0; i < 4; i++) {
        const char* p = Ab + arow_b + (ih * 64 + i * 16) * 128;
        a[0][i] = *(const s16x8*)(p + k0);
        a[1][i] = *(const s16x8*)(p + k1);
    }
}
__device__ __forceinline__ void read_bf(const char* Bb, int brow_b, int k0, int jh, s16x8 (&b)[2][2])
{
    const int k1 = k0 ^ 64;
#pragma unroll
    for (int j = 0; j < 2; j++) {
        const char* p = Bb + brow_b + (jh * 32 + j * 16) * 128;
        b[0][j] = *(const s16x8*)(p + k0);
        b[1][j] = *(const s16x8*)(p + k1);
    }
}

template<int IH, int JH>
__device__ __forceinline__ void mfma_quad(s16x8 (&a)[2][4], s16x8 (&b)[2][2], f32x4 (&acc)[8][4])
{
    __builtin_amdgcn_s_setprio(1);
#pragma unroll
    for (int kk = 0; kk < 2; kk++)
#pragma unroll
        for (int i = 0; i < 4; i++)
#pragma unroll
            for (int j = 0; j < 2; j++)
                acc[IH * 4 + i][JH * 2 + j] = __builtin_amdgcn_mfma_f32_16x16x32_bf16(
                    a[kk][i], b[kk][j], acc[IH * 4 + i][JH * 2 + j], 0, 0, 0);
    __builtin_amdgcn_s_setprio(0);
}

template<int LDB, bool S1, bool S2, int VM>
__device__ __forceinline__ void gwindow(const char* AgK, const char* BgK,
    char* Acur, char* Bcur, char* Anxt, char* Bnxt,
    int arow_b, int brow_b, int k0, int tid, f32x4 (&acc)[8][4])
{
    s16x8 a[2][4], b0[2][2], b1[2][2];
    read_af(Acur, arow_b, k0, 0, a);
    read_bf(Bcur, brow_b, k0, 0, b0);
    if constexpr (S1) stage_region<LDB, true >(AgK + 128, Anxt, 1, tid);
    __builtin_amdgcn_s_barrier();
    mfma_quad<0, 0>(a, b0, acc);
    __builtin_amdgcn_s_barrier();
    read_bf(Bcur, brow_b, k0, 1, b1);
    if constexpr (S1) stage_region<LDB, false>(BgK + 128, Bnxt, 1, tid);
    __builtin_amdgcn_s_barrier();
    mfma_quad<0, 1>(a, b1, acc);
    __builtin_amdgcn_s_barrier();
    read_af(Acur, arow_b, k0, 1, a);
    if constexpr (S2) stage_region<LDB, true >(AgK + 256, Acur, 0, tid);
    __builtin_amdgcn_s_barrier();
    mfma_quad<1, 1>(a, b1, acc);
    __builtin_amdgcn_s_barrier();
    if constexpr (S2) stage_region<LDB, false>(BgK + 256, Bcur, 0, tid);
    __builtin_amdgcn_s_barrier();
    mfma_quad<1, 0>(a, b0, acc);
    if constexpr (VM >= 0) VMCNT(VM);
    __builtin_amdgcn_s_barrier();
}

template<int LDB>
__device__ __forceinline__ void gemm_mainloop(const char* Ag, const char* Bg,
    char* smem, int KT, int tid, int arow_b, int brow_b, int k0, f32x4 (&acc)[8][4])
{
    stage_region<LDB, true >(Ag,       smem,          0, tid);
    stage_region<LDB, false>(Bg,       smem + 65536,  0, tid);
    stage_region<LDB, true >(Ag,       smem,          1, tid);
    stage_region<LDB, false>(Bg,       smem + 65536,  1, tid);
    stage_region<LDB, true >(Ag + 128, smem + 32768,  0, tid);
    stage_region<LDB, false>(Bg + 128, smem + 98304,  0, tid);
    VMCNT(4);
    __builtin_amdgcn_s_barrier();

    int cur = 0;
    for (int kt = 0; kt < KT - 2; ++kt) {
        char* Acur = smem + (cur << 15);
        char* Anxt = smem + ((cur ^ 1) << 15);
        char* Bcur = smem + 65536 + (cur << 15);
        char* Bnxt = smem + 65536 + ((cur ^ 1) << 15);
        gwindow<LDB, true, true, 4>(Ag + (size_t)kt * 128, Bg + (size_t)kt * 128,
            Acur, Bcur, Anxt, Bnxt, arow_b, brow_b, k0, tid, acc);
        cur ^= 1;
    }
    {
        char* Acur = smem + (cur << 15);
        char* Anxt = smem + ((cur ^ 1) << 15);
        char* Bcur = smem + 65536 + (cur << 15);
        char* Bnxt = smem + 65536 + ((cur ^ 1) << 15);
        gwindow<LDB, true, false, 0>(Ag + (size_t)(KT - 2) * 128, Bg + (size_t)(KT - 2) * 128,
            Acur, Bcur, Anxt, Bnxt, arow_b, brow_b, k0, tid, acc);
        cur ^= 1;
    }
    {
        char* Acur = smem + (cur << 15);
        char* Anxt = smem + ((cur ^ 1) << 15);
        char* Bcur = smem + 65536 + (cur << 15);
        char* Bnxt = smem + 65536 + ((cur ^ 1) << 15);
        gwindow<LDB, false, false, -1>(Ag + (size_t)(KT - 1) * 128, Bg + (size_t)(KT - 1) * 128,
            Acur, Bcur, Anxt, Bnxt, arow_b, brow_b, k0, tid, acc);
    }
}

// ---------------------------------------------------------------------------
// Kernel 1: G = gelu(Xb @ W1[e] + b1[e]) -> bf16.  SINGLE ROUND: 256 blocks,
// each block handles 3 nt-chunks sequentially (full K-loop + NT epilogue per
// chunk). A panels L2-warm after chunk 0; 4 B panels/XCD x 8-block multicast,
// time-synchronized by the common chunk loop.
// ---------------------------------------------------------------------------
__global__ __launch_bounds__(512, 2) void moe_gemm1(
    const unsigned short* __restrict__ Xb,
    const int*   __restrict__ labels,
    const int*   __restrict__ perm,
    const unsigned short* __restrict__ W1T,  // [E][FFN][HID]
    const float* __restrict__ B1,
    unsigned short* __restrict__ G)
{
    extern __shared__ char smem[];
    const int L = blockIdx.x;               // 0..255
    const int xcd  = L & 7;
    const int slot = L >> 3;                // 0..31
    const int pair = slot >> 2;             // 0..7
    const int bs  = perm[xcd * 4 + (pair >> 1)];
    const int mt  = pair & 1;
    const int ntg = slot & 3;               // nt group
    const int e   = labels[bs];

    const char* Ag = (const char*)(Xb + ((size_t)bs * SEQ + (size_t)mt * 256) * HID);

    const int tid = threadIdx.x;
    const int lane = tid & 63, w = tid >> 6;
    const int wm = (w >> 2) * 128, wn = (w & 3) * 64;
    const int fr = lane & 15, fq = lane >> 4;
    const int arow_b = (wm + fr) * 128, brow_b = (wn + fr) * 128;
    const int k0 = (fq * 16) ^ ((fr & 7) << 4);

    for (int chunk = 0; chunk < 3; ++chunk) {
        const int nt = ntg * 3 + chunk;     // 0..11
        const char* Bg = (const char*)(W1T + (size_t)e * FFN * HID + (size_t)nt * 256 * HID);

        f32x4 acc[8][4];
#pragma unroll
        for (int i2 = 0; i2 < 8; i2++)
#pragma unroll
            for (int j = 0; j < 4; j++) acc[i2][j] = (f32x4)0.0f;

        gemm_mainloop<HID * 2>(Ag, Bg, smem, HID / 64, tid, arow_b, brow_b, k0, acc);

        // ---- epilogue: bias+gelu -> LDS bf16 tile [256][256] (swizzled) ----
        const float* b1g = B1 + (size_t)e * FFN + (size_t)nt * 256;
        float bias[4];
#pragma unroll
        for (int nj = 0; nj < 4; nj++) bias[nj] = b1g[wn + nj * 16 + fr];
#pragma unroll
        for (int mi = 0; mi < 8; mi++)
#pragma unroll
            for (int nj = 0; nj < 4; nj++) {
                const int col = wn + nj * 16 + fr;
#pragma unroll
                for (int r2 = 0; r2 < 4; r2++) {
                    const int row = wm + mi * 16 + fq * 4 + r2;
                    float v = acc[mi][nj][r2] + bias[nj];
                    int byte = row * 512 + ((col * 2) ^ ((row & 7) << 4));
                    *(unsigned short*)(smem + byte) = f2bf(gelu_fast(v));
                }
            }
        __syncthreads();
        // ---- stream out: full-line nontemporal ----
        char* Cgb = (char*)(G + ((size_t)bs * SEQ + (size_t)mt * 256) * FFN + (size_t)nt * 256);
#pragma unroll
        for (int it = 0; it < 16; it++) {
            int c2 = tid + it * 512;        // 0..8191
            int row = c2 >> 5;
            int cb  = (c2 & 31) * 16;
            s16x8 v = *(const s16x8*)(smem + row * 512 + (cb ^ ((row & 7) << 4)));
            __builtin_nontemporal_store(v, (s16x8*)(Cgb + (size_t)row * (FFN * 2) + cb));
        }
        __syncthreads();                    // LDS reused by next chunk's prologue
    }
}

// ---------------------------------------------------------------------------
// Kernel 2: Out = G @ W2[e] + b2[e] -> fp32; LDS-coalesced NT epilogue.
// ---------------------------------------------------------------------------
__global__ __launch_bounds__(512, 2) void moe_gemm2(
    const unsigned short* __restrict__ G,
    const int*   __restrict__ labels,
    const int*   __restrict__ perm,
    const unsigned short* __restrict__ W2T,  // [E][HID][FFN]
    const float* __restrict__ B2,
    float* __restrict__ Out)
{
    extern __shared__ char smem[];
    const int L = blockIdx.x;
    const int xcd = L & 7, s = L >> 3;       // s in [0,24)
    const int bs = perm[xcd * 4 + s / 6];
    const int rr = s % 6;
    const int mt = rr / 3, nt = rr % 3;
    const int e  = labels[bs];

    const char* Ag = (const char*)(G + ((size_t)bs * SEQ + (size_t)mt * 256) * FFN);
    const char* Bg = (const char*)(W2T + (size_t)e * HID * FFN + (size_t)nt * 256 * FFN);

    const int tid = threadIdx.x;
    const int lane = tid & 63, w = tid >> 6;
    const int wm = (w >> 2) * 128, wn = (w & 3) * 64;
    const int fr = lane & 15, fq = lane >> 4;
    const int arow_b = (wm + fr) * 128, brow_b = (wn + fr) * 128;
    const int k0 = (fq * 16) ^ ((fr & 7) << 4);

    f32x4 acc[8][4];
#pragma unroll
    for (int i = 0; i < 8; i++)
#pragma unroll
        for (int j = 0; j < 4; j++) acc[i][j] = (f32x4)0.0f;

    gemm_mainloop<FFN * 2>(Ag, Bg, smem, FFN / 64, tid, arow_b, brow_b, k0, acc);

    const float* b2g = B2 + (size_t)e * HID + (size_t)nt * 256;
    float bias[4];
#pragma unroll
    for (int nj = 0; nj < 4; nj++) bias[nj] = b2g[wn + nj * 16 + fr];
    char* Cgb = (char*)(Out + ((size_t)bs * SEQ + (size_t)mt * 256) * HID + (size_t)nt * 256);

#pragma unroll
    for (int half = 0; half < 2; ++half) {
        if ((wn >> 7) == half) {
#pragma unroll
            for (int mi = 0; mi < 8; mi++)
#pragma unroll
                for (int nj = 0; nj < 4; nj++) {
                    const int lcol = (wn & 127) + nj * 16 + fr;
#pragma unroll
                    for (int r2 = 0; r2 < 4; r2++) {
                        const int row = wm + mi * 16 + fq * 4 + r2;
                        int byte = row * 512 + ((lcol * 4) ^ ((row & 7) << 4));
                        *(float*)(smem + byte) = acc[mi][nj][r2] + bias[nj];
                    }
                }
        }
        __syncthreads();
#pragma unroll
        for (int it = 0; it < 16; it++) {
            int chunk = tid + it * 512;
            int row = chunk >> 5;
            int cb  = (chunk & 31) * 16;
            f32x4 v = *(const f32x4*)(smem + row * 512 + (cb ^ ((row & 7) << 4)));
            __builtin_nontemporal_store(v, (f32x4*)(Cgb + (size_t)row * (HID * 4) + half * 512 + cb));
        }
        if (half == 0) __syncthreads();
    }
}

extern "C" void kernel_launch(void* const* d_in, const int* in_sizes, int n_in,
                              void* d_out, int out_size, void* d_ws, size_t ws_size,
                              hipStream_t stream) {
    const float* X      = (const float*)d_in[0];
    const int*   labels = (const int*)  d_in[1];
    const float* W1     = (const float*)d_in[2];
    const float* B1     = (const float*)d_in[3];
    const float* W2     = (const float*)d_in[4];
    const float* B2     = (const float*)d_in[5];
    float* Out = (float*)d_out;

    char* ws = (char*)d_ws;
    unsigned short* Xb  = (unsigned short*)(ws);               // 25,165,824 B
    unsigned short* W1T = (unsigned short*)(ws + 25165824);    // 37,748,736 B
    unsigned short* W2T = (unsigned short*)(ws + 62914560);    // 37,748,736 B
    unsigned short* G   = (unsigned short*)(ws + 100663296);   // 100,663,296 B
    int*            perm = (int*)(ws + 201326592);             // 128 B

    (void)hipFuncSetAttribute((const void*)moe_gemm1,
        hipFuncAttributeMaxDynamicSharedMemorySize, 131072);
    (void)hipFuncSetAttribute((const void*)moe_gemm2,
        hipFuncAttributeMaxDynamicSharedMemorySize, 131072);

    sort_labels_kernel<<<1, 64, 0, stream>>>(labels, perm);
    cvt_x_kernel<<<2048, 256, 0, stream>>>(X, Xb, NB * SEQ * HID / 8);
    cvt_transpose_kernel<<<dim3(FFN / 64, HID / 64, NEXP), 256, 0, stream>>>(W1, W1T, HID, FFN);
    cvt_transpose_kernel<<<dim3(HID / 64, FFN / 64, NEXP), 256, 0, stream>>>(W2, W2T, FFN, HID);

    moe_gemm1<<<256, dim3(512), 131072, stream>>>(Xb, labels, perm, W1T, B1, G);
    moe_gemm2<<<192, dim3(512), 131072, stream>>>(G, labels, perm, W2T, B2, Out);
}

// Round 12
// 230.106 us; speedup vs baseline: 1.5003x; 1.5003x over previous
//
#include <hip/hip_runtime.h>
#include <hip/hip_bf16.h>

#define NB   32
#define SEQ  512
#define HID  768
#define FFN  3072
#define NEXP 8

typedef float f32x4 __attribute__((ext_vector_type(4)));
typedef short s16x8 __attribute__((ext_vector_type(8)));

__device__ __forceinline__ unsigned short f2bf(float f) {
    return __builtin_bit_cast(unsigned short, (__bf16)f);
}

__device__ __forceinline__ float fast_exp2(float x) {
    float r; asm("v_exp_f32 %0, %1" : "=v"(r) : "v"(x)); return r;
}
__device__ __forceinline__ float fast_rcp(float x) {
    float r; asm("v_rcp_f32 %0, %1" : "=v"(r) : "v"(x)); return r;
}

// tanh-gelu, overflow-free (exp2 arg <= 0). |error| vs exact-erf gelu ~2e-4.
__device__ __forceinline__ float gelu_fast(float v) {
    float u  = v * (0.7978845608f + 0.0356774081f * v * v);
    float t  = fast_exp2(-2.8853900817779268f * fabsf(u));
    float T  = (1.0f - t) * fast_rcp(1.0f + t);
    return 0.5f * v + 0.5f * fabsf(v) * T;
}

#define GLOAD16(gp, lp) __builtin_amdgcn_global_load_lds( \
    (const __attribute__((address_space(1))) unsigned int*)(gp), \
    (__attribute__((address_space(3))) unsigned int*)(lp), 16, 0, 0)

#define VMCNT(N) asm volatile("s_waitcnt vmcnt(%0)" :: "i"(N) : "memory")

// ---------------------------------------------------------------------------
// stable counting-sort permutation of sentences by expert label (1 wave)
// ---------------------------------------------------------------------------
__global__ void sort_labels_kernel(const int* __restrict__ labels, int* __restrict__ perm)
{
    int i = threadIdx.x;
    if (i < NB) {
        int li = labels[i];
        int rank = 0;
        for (int j = 0; j < NB; j++) {
            int lj = labels[j];
            if (lj < li || (lj == li && j < i)) rank++;
        }
        perm[rank] = i;
    }
}

// ---------------------------------------------------------------------------
// convert X fp32 -> bf16 (full-chip)
// ---------------------------------------------------------------------------
__global__ __launch_bounds__(256) void cvt_x_kernel(
    const float* __restrict__ X, unsigned short* __restrict__ Xb, int n8)
{
    int idx = blockIdx.x * blockDim.x + threadIdx.x;
    int stride = gridDim.x * blockDim.x;
    for (int i = idx; i < n8; i += stride) {
        f32x4 a = *(const f32x4*)(X + (size_t)i * 8);
        f32x4 b = *(const f32x4*)(X + (size_t)i * 8 + 4);
        unsigned short o[8];
#pragma unroll
        for (int v = 0; v < 4; v++) o[v] = f2bf(a[v]);
#pragma unroll
        for (int v = 0; v < 4; v++) o[4 + v] = f2bf(b[v]);
        *(s16x8*)(Xb + (size_t)i * 8) = *(s16x8*)o;
    }
}

// ---------------------------------------------------------------------------
// convert + transpose: in [R][C] fp32 -> out [C][R] bf16 per slab
// ---------------------------------------------------------------------------
__global__ __launch_bounds__(256) void cvt_transpose_kernel(
    const float* __restrict__ W, unsigned short* __restrict__ WT, int R, int C)
{
    __shared__ unsigned short tile[64][65];
    const int cb = blockIdx.x * 64, rb = blockIdx.y * 64;
    const float* src = W + (size_t)blockIdx.z * R * C;
    unsigned short* dst = WT + (size_t)blockIdx.z * R * C;
    const int x = threadIdx.x & 63, y0 = threadIdx.x >> 6;
#pragma unroll
    for (int i = 0; i < 16; i++) {
        int r = y0 + i * 4;
        tile[r][x] = f2bf(src[(size_t)(rb + r) * C + cb + x]);
    }
    __syncthreads();
#pragma unroll
    for (int i = 0; i < 16; i++) {
        int c = y0 + i * 4;
        dst[(size_t)(cb + c) * R + rb + x] = tile[x][c];
    }
}

// ---------------------------------------------------------------------------
// Shared 256x256 8-phase window machinery (BK=64, 8 waves, 2 x 64KB LDS bufs)
// ---------------------------------------------------------------------------
template<int LDB, bool ISA>
__device__ __forceinline__ void stage_region(const char* g, char* lds, int half, int tid)
{
#pragma unroll
    for (int p = 0; p < 2; p++) {
        int L  = p * 8192 + tid * 16;
        int rr = L >> 7;
        int cb = L & 127;
        int row = ISA ? ((rr & 63) + ((rr >> 6) << 7) + half * 64)
                      : ((rr & 31) + ((rr >> 5) << 6) + half * 32);
        int cbs = cb ^ ((row & 7) << 4);
        GLOAD16(g + (size_t)row * LDB + cbs, lds + (size_t)row * 128 + cb);
    }
}

__device__ __forceinline__ void read_af(const char* Ab, int arow_b, int k0, int ih, s16x8 (&a)[2][4])
{
    const int k1 = k0 ^ 64;
#pragma unroll
    for (int i = 0; i < 4; i++) {
        const char* p = Ab + arow_b + (ih * 64 + i * 16) * 128;
        a[0][i] = *(const s16x8*)(p + k0);
        a[1][i] = *(const s16x8*)(p + k1);
    }
}
__device__ __forceinline__ void read_bf(const char* Bb, int brow_b, int k0, int jh, s16x8 (&b)[2][2])
{
    const int k1 = k0 ^ 64;
#pragma unroll
    for (int j = 0; j < 2; j++) {
        const char* p = Bb + brow_b + (jh * 32 + j * 16) * 128;
        b[0][j] = *(const s16x8*)(p + k0);
        b[1][j] = *(const s16x8*)(p + k1);
    }
}

template<int IH, int JH>
__device__ __forceinline__ void mfma_quad(s16x8 (&a)[2][4], s16x8 (&b)[2][2], f32x4 (&acc)[8][4])
{
    __builtin_amdgcn_s_setprio(1);
#pragma unroll
    for (int kk = 0; kk < 2; kk++)
#pragma unroll
        for (int i = 0; i < 4; i++)
#pragma unroll
            for (int j = 0; j < 2; j++)
                acc[IH * 4 + i][JH * 2 + j] = __builtin_amdgcn_mfma_f32_16x16x32_bf16(
                    a[kk][i], b[kk][j], acc[IH * 4 + i][JH * 2 + j], 0, 0, 0);
    __builtin_amdgcn_s_setprio(0);
}

// generic window: explicit stage pointers for tiles w+1 ("1"-halves -> nxt)
// and w+2 ("0"-halves -> cur). Guards identical to the proven R10 schedule.
template<int LDB, bool S1, bool S2, int VM>
__device__ __forceinline__ void gwindowP(
    const char* pA1, const char* pB1, const char* pA0, const char* pB0,
    char* Acur, char* Bcur, char* Anxt, char* Bnxt,
    int arow_b, int brow_b, int k0, int tid, f32x4 (&acc)[8][4])
{
    s16x8 a[2][4], b0[2][2], b1[2][2];
    read_af(Acur, arow_b, k0, 0, a);
    read_bf(Bcur, brow_b, k0, 0, b0);
    if constexpr (S1) stage_region<LDB, true >(pA1, Anxt, 1, tid);
    __builtin_amdgcn_s_barrier();
    mfma_quad<0, 0>(a, b0, acc);
    __builtin_amdgcn_s_barrier();
    read_bf(Bcur, brow_b, k0, 1, b1);
    if constexpr (S1) stage_region<LDB, false>(pB1, Bnxt, 1, tid);
    __builtin_amdgcn_s_barrier();
    mfma_quad<0, 1>(a, b1, acc);
    __builtin_amdgcn_s_barrier();
    read_af(Acur, arow_b, k0, 1, a);
    if constexpr (S2) stage_region<LDB, true >(pA0, Acur, 0, tid);
    __builtin_amdgcn_s_barrier();
    mfma_quad<1, 1>(a, b1, acc);
    __builtin_amdgcn_s_barrier();
    if constexpr (S2) stage_region<LDB, false>(pB0, Bcur, 0, tid);
    __builtin_amdgcn_s_barrier();
    mfma_quad<1, 0>(a, b0, acc);
    if constexpr (VM >= 0) VMCNT(VM);
    __builtin_amdgcn_s_barrier();
}

// ---------------------------------------------------------------------------
// Kernel 1: persistent 36-window pipeline. 256 blocks (1/CU, single round).
// Each block: fixed (bs, mt, ntg); windows w = chunk*12 + kt, chunk = nt
// offset, pipeline NEVER drains across chunks. Register-direct epilogue at
// w = 11, 23, 35 (acc -> gelu -> G), then VMCNT(0) re-bases the guards.
// ---------------------------------------------------------------------------
__global__ __launch_bounds__(512, 2) void moe_gemm1(
    const unsigned short* __restrict__ Xb,
    const int*   __restrict__ labels,
    const int*   __restrict__ perm,
    const unsigned short* __restrict__ W1T,  // [E][FFN][HID]
    const float* __restrict__ B1,
    unsigned short* __restrict__ G)
{
    extern __shared__ char smem[];
    const int L = blockIdx.x;               // 0..255
    const int xcd  = L & 7;
    const int slot = L >> 3;                // 0..31
    const int pair = slot >> 2;             // 0..7
    const int bs  = perm[xcd * 4 + (pair >> 1)];
    const int mt  = pair & 1;
    const int ntg = slot & 3;
    const int e   = labels[bs];
    constexpr int LDB = HID * 2;

    const char* Ag  = (const char*)(Xb + ((size_t)bs * SEQ + (size_t)mt * 256) * HID);
    const char* W1e = (const char*)(W1T + (size_t)e * FFN * HID);

    const int tid = threadIdx.x;
    const int lane = tid & 63, w = tid >> 6;
    const int wm = (w >> 2) * 128, wn = (w & 3) * 64;
    const int fr = lane & 15, fq = lane >> 4;
    const int arow_b = (wm + fr) * 128, brow_b = (wn + fr) * 128;
    const int k0 = (fq * 16) ^ ((fr & 7) << 4);

    auto pA = [&](int ww) { return Ag + (size_t)(ww % 12) * 128; };
    auto pB = [&](int ww) {
        return W1e + (size_t)(ntg * 3 + ww / 12) * 256 * LDB + (size_t)(ww % 12) * 128;
    };

    // prologue: tiles for windows 0 (both halves) and 1 ("0" halves)
    stage_region<LDB, true >(pA(0), smem,          0, tid);
    stage_region<LDB, false>(pB(0), smem + 65536,  0, tid);
    stage_region<LDB, true >(pA(0), smem,          1, tid);
    stage_region<LDB, false>(pB(0), smem + 65536,  1, tid);
    stage_region<LDB, true >(pA(1), smem + 32768,  0, tid);
    stage_region<LDB, false>(pB(1), smem + 98304,  0, tid);
    VMCNT(4);
    __builtin_amdgcn_s_barrier();

    f32x4 acc[8][4];
#pragma unroll
    for (int i2 = 0; i2 < 8; i2++)
#pragma unroll
        for (int j = 0; j < 4; j++) acc[i2][j] = (f32x4)0.0f;

    auto epilogue = [&](int chunk) {
        const int nt = ntg * 3 + chunk;
        const float* b1g = B1 + (size_t)e * FFN + (size_t)nt * 256;
        unsigned short* Cg = G + ((size_t)bs * SEQ + (size_t)mt * 256) * FFN + (size_t)nt * 256;
        float bias[4];
#pragma unroll
        for (int nj = 0; nj < 4; nj++) bias[nj] = b1g[wn + nj * 16 + fr];
#pragma unroll
        for (int mi = 0; mi < 8; mi++)
#pragma unroll
            for (int nj = 0; nj < 4; nj++) {
                const int col = wn + nj * 16 + fr;
#pragma unroll
                for (int r2 = 0; r2 < 4; r2++) {
                    const int row = wm + mi * 16 + fq * 4 + r2;
                    float v = acc[mi][nj][r2] + bias[nj];
                    Cg[(size_t)row * FFN + col] = f2bf(gelu_fast(v));
                    acc[mi][nj][r2] = 0.0f;
                }
            }
    };

    for (int ww = 0; ww < 34; ++ww) {
        const int cur = ww & 1;
        char* Acur = smem + (cur << 15);
        char* Anxt = smem + ((cur ^ 1) << 15);
        char* Bcur = smem + 65536 + (cur << 15);
        char* Bnxt = smem + 65536 + ((cur ^ 1) << 15);
        gwindowP<LDB, true, true, 4>(pA(ww + 1), pB(ww + 1), pA(ww + 2), pB(ww + 2),
            Acur, Bcur, Anxt, Bnxt, arow_b, brow_b, k0, tid, acc);
        if (ww == 11 || ww == 23) {
            epilogue(ww / 12);
            VMCNT(0);       // drain stores+bias loads; future tiles already in LDS
        }
    }
    {   // window 34: stage only window 35's "1" halves; drain loads
        char* Acur = smem + ((34 & 1) << 15);
        char* Anxt = smem + (((34 & 1) ^ 1) << 15);
        char* Bcur = smem + 65536 + ((34 & 1) << 15);
        char* Bnxt = smem + 65536 + (((34 & 1) ^ 1) << 15);
        gwindowP<LDB, true, false, 0>(pA(35), pB(35), nullptr, nullptr,
            Acur, Bcur, Anxt, Bnxt, arow_b, brow_b, k0, tid, acc);
    }
    {   // window 35: no stages
        char* Acur = smem + ((35 & 1) << 15);
        char* Anxt = smem + (((35 & 1) ^ 1) << 15);
        char* Bcur = smem + 65536 + ((35 & 1) << 15);
        char* Bnxt = smem + 65536 + (((35 & 1) ^ 1) << 15);
        gwindowP<LDB, false, false, -1>(nullptr, nullptr, nullptr, nullptr,
            Acur, Bcur, Anxt, Bnxt, arow_b, brow_b, k0, tid, acc);
    }
    epilogue(2);
}

// ---------------------------------------------------------------------------
// Kernel 2: Out = G @ W2[e] + b2[e] -> fp32 (R10 version, unchanged)
// ---------------------------------------------------------------------------
template<int LDB>
__device__ __forceinline__ void gemm_mainloop2(const char* Ag, const char* Bg,
    char* smem, int KT, int tid, int arow_b, int brow_b, int k0, f32x4 (&acc)[8][4])
{
    stage_region<LDB, true >(Ag,       smem,          0, tid);
    stage_region<LDB, false>(Bg,       smem + 65536,  0, tid);
    stage_region<LDB, true >(Ag,       smem,          1, tid);
    stage_region<LDB, false>(Bg,       smem + 65536,  1, tid);
    stage_region<LDB, true >(Ag + 128, smem + 32768,  0, tid);
    stage_region<LDB, false>(Bg + 128, smem + 98304,  0, tid);
    VMCNT(4);
    __builtin_amdgcn_s_barrier();

    int cur = 0;
    for (int kt = 0; kt < KT - 2; ++kt) {
        char* Acur = smem + (cur << 15);
        char* Anxt = smem + ((cur ^ 1) << 15);
        char* Bcur = smem + 65536 + (cur << 15);
        char* Bnxt = smem + 65536 + ((cur ^ 1) << 15);
        gwindowP<LDB, true, true, 4>(Ag + (size_t)(kt + 1) * 128, Bg + (size_t)(kt + 1) * 128,
            Ag + (size_t)(kt + 2) * 128, Bg + (size_t)(kt + 2) * 128,
            Acur, Bcur, Anxt, Bnxt, arow_b, brow_b, k0, tid, acc);
        cur ^= 1;
    }
    {
        char* Acur = smem + (cur << 15);
        char* Anxt = smem + ((cur ^ 1) << 15);
        char* Bcur = smem + 65536 + (cur << 15);
        char* Bnxt = smem + 65536 + ((cur ^ 1) << 15);
        gwindowP<LDB, true, false, 0>(Ag + (size_t)(KT - 1) * 128, Bg + (size_t)(KT - 1) * 128,
            nullptr, nullptr, Acur, Bcur, Anxt, Bnxt, arow_b, brow_b, k0, tid, acc);
        cur ^= 1;
    }
    {
        char* Acur = smem + (cur << 15);
        char* Anxt = smem + ((cur ^ 1) << 15);
        char* Bcur = smem + 65536 + (cur << 15);
        char* Bnxt = smem + 65536 + ((cur ^ 1) << 15);
        gwindowP<LDB, false, false, -1>(nullptr, nullptr, nullptr, nullptr,
            Acur, Bcur, Anxt, Bnxt, arow_b, brow_b, k0, tid, acc);
    }
}

__global__ __launch_bounds__(512, 2) void moe_gemm2(
    const unsigned short* __restrict__ G,
    const int*   __restrict__ labels,
    const int*   __restrict__ perm,
    const unsigned short* __restrict__ W2T,  // [E][HID][FFN]
    const float* __restrict__ B2,
    float* __restrict__ Out)
{
    extern __shared__ char smem[];
    const int L = blockIdx.x;
    const int xcd = L & 7, s = L >> 3;       // s in [0,24)
    const int bs = perm[xcd * 4 + s / 6];
    const int rr = s % 6;
    const int mt = rr / 3, nt = rr % 3;
    const int e  = labels[bs];

    const char* Ag = (const char*)(G + ((size_t)bs * SEQ + (size_t)mt * 256) * FFN);
    const char* Bg = (const char*)(W2T + (size_t)e * HID * FFN + (size_t)nt * 256 * FFN);

    const int tid = threadIdx.x;
    const int lane = tid & 63, w = tid >> 6;
    const int wm = (w >> 2) * 128, wn = (w & 3) * 64;
    const int fr = lane & 15, fq = lane >> 4;
    const int arow_b = (wm + fr) * 128, brow_b = (wn + fr) * 128;
    const int k0 = (fq * 16) ^ ((fr & 7) << 4);

    f32x4 acc[8][4];
#pragma unroll
    for (int i = 0; i < 8; i++)
#pragma unroll
        for (int j = 0; j < 4; j++) acc[i][j] = (f32x4)0.0f;

    gemm_mainloop2<FFN * 2>(Ag, Bg, smem, FFN / 64, tid, arow_b, brow_b, k0, acc);

    const float* b2g = B2 + (size_t)e * HID + (size_t)nt * 256;
    float bias[4];
#pragma unroll
    for (int nj = 0; nj < 4; nj++) bias[nj] = b2g[wn + nj * 16 + fr];
    char* Cgb = (char*)(Out + ((size_t)bs * SEQ + (size_t)mt * 256) * HID + (size_t)nt * 256);

#pragma unroll
    for (int half = 0; half < 2; ++half) {
        if ((wn >> 7) == half) {
#pragma unroll
            for (int mi = 0; mi < 8; mi++)
#pragma unroll
                for (int nj = 0; nj < 4; nj++) {
                    const int lcol = (wn & 127) + nj * 16 + fr;
#pragma unroll
                    for (int r2 = 0; r2 < 4; r2++) {
                        const int row = wm + mi * 16 + fq * 4 + r2;
                        int byte = row * 512 + ((lcol * 4) ^ ((row & 7) << 4));
                        *(float*)(smem + byte) = acc[mi][nj][r2] + bias[nj];
                    }
                }
        }
        __syncthreads();
#pragma unroll
        for (int it = 0; it < 16; it++) {
            int chunk = tid + it * 512;
            int row = chunk >> 5;
            int cb  = (chunk & 31) * 16;
            f32x4 v = *(const f32x4*)(smem + row * 512 + (cb ^ ((row & 7) << 4)));
            __builtin_nontemporal_store(v, (f32x4*)(Cgb + (size_t)row * (HID * 4) + half * 512 + cb));
        }
        if (half == 0) __syncthreads();
    }
}

extern "C" void kernel_launch(void* const* d_in, const int* in_sizes, int n_in,
                              void* d_out, int out_size, void* d_ws, size_t ws_size,
                              hipStream_t stream) {
    const float* X      = (const float*)d_in[0];
    const int*   labels = (const int*)  d_in[1];
    const float* W1     = (const float*)d_in[2];
    const float* B1     = (const float*)d_in[3];
    const float* W2     = (const float*)d_in[4];
    const float* B2     = (const float*)d_in[5];
    float* Out = (float*)d_out;

    char* ws = (char*)d_ws;
    unsigned short* Xb  = (unsigned short*)(ws);               // 25,165,824 B
    unsigned short* W1T = (unsigned short*)(ws + 25165824);    // 37,748,736 B
    unsigned short* W2T = (unsigned short*)(ws + 62914560);    // 37,748,736 B
    unsigned short* G   = (unsigned short*)(ws + 100663296);   // 100,663,296 B
    int*            perm = (int*)(ws + 201326592);             // 128 B

    (void)hipFuncSetAttribute((const void*)moe_gemm1,
        hipFuncAttributeMaxDynamicSharedMemorySize, 131072);
    (void)hipFuncSetAttribute((const void*)moe_gemm2,
        hipFuncAttributeMaxDynamicSharedMemorySize, 131072);

    sort_labels_kernel<<<1, 64, 0, stream>>>(labels, perm);
    cvt_x_kernel<<<2048, 256, 0, stream>>>(X, Xb, NB * SEQ * HID / 8);
    cvt_transpose_kernel<<<dim3(FFN / 64, HID / 64, NEXP), 256, 0, stream>>>(W1, W1T, HID, FFN);
    cvt_transpose_kernel<<<dim3(HID / 64, FFN / 64, NEXP), 256, 0, stream>>>(W2, W2T, FFN, HID);

    moe_gemm1<<<256, dim3(512), 131072, stream>>>(Xb, labels, perm, W1T, B1, G);
    moe_gemm2<<<192, dim3(512), 131072, stream>>>(G, labels, perm, W2T, B2, Out);
}